// Round 5
// baseline (623.781 us; speedup 1.0000x reference)
//
#include <hip/hip_runtime.h>
#include <cstdint>
#include <cstddef>

typedef _Float16 f16;
typedef __attribute__((ext_vector_type(4)))  _Float16 f16x4;
typedef __attribute__((ext_vector_type(8)))  _Float16 f16x8;
typedef __attribute__((ext_vector_type(2)))  __fp16   fp16v2;
typedef __attribute__((ext_vector_type(4)))  float    f32x4;
typedef __attribute__((ext_vector_type(16))) float    f32x16;

static constexpr int BB = 16, LL = 2048, DIN = 512, HH = 256, DOUT = 1024;
static constexpr float SCALE = 0.0625f;   // 1/sqrt(256)
#define NEG_BIG (-1e30f)

__device__ __forceinline__ void gload16(const void* g, void* l) {
  __builtin_amdgcn_global_load_lds(
      (const __attribute__((address_space(1))) unsigned int*)g,
      (__attribute__((address_space(3))) unsigned int*)l, 16, 0, 0);
}

__device__ __forceinline__ unsigned pk2(float a, float b) {
  union { fp16v2 v; unsigned u; } c;
  c.v = __builtin_amdgcn_cvt_pkrtz(a, b);
  return c.u;
}

// ---- W transpose+cast: W[512][256] f32 -> WT[256][512] f16
__global__ void wt_kernel(const float* __restrict__ W, f16* __restrict__ WT) {
  int g = blockIdx.x * 256 + threadIdx.x;     // 131072 total
  int d = g >> 8, h = g & 255;
  WT[h * 512 + d] = (f16)W[g];
}

// ---- V transpose+cast: mem[b][m][512] f32 -> VT[b][512][2048] f16
__global__ void vt_kernel(const float* __restrict__ mem, f16* __restrict__ VT) {
  int m0 = blockIdx.x * 32, d0 = blockIdx.y * 32, b = blockIdx.z;
  __shared__ f16 t[32][36];
  int tid = threadIdx.x;
  {
    int r = tid >> 3, c4 = (tid & 7) * 4;
    float4 v = *(const float4*)(mem + (size_t)(b * LL + m0 + r) * DIN + d0 + c4);
    t[c4 + 0][r] = (f16)v.x; t[c4 + 1][r] = (f16)v.y;
    t[c4 + 2][r] = (f16)v.z; t[c4 + 3][r] = (f16)v.w;
  }
  __syncthreads();
  {
    int d = tid >> 3, seg = tid & 7;
    f16x4 hv = *(const f16x4*)&t[d][seg * 4];
    *(f16x4*)(VT + (size_t)(b * 512 + d0 + d) * 2048 + m0 + seg * 4) = hv;
  }
}

// ---- projection: Out[M][256] = f16(relu(X[M][512] * W)), W given as WT[256][512] f16
__global__ __launch_bounds__(256, 2) void proj_kernel(const float* __restrict__ X,
                                                      const f16* __restrict__ WT,
                                                      f16* __restrict__ Out) {
  const int Rbase = blockIdx.x * 128, Cbase = blockIdx.y * 128;
  __shared__ f16 a_t[128 * 40];
  __shared__ f16 b_t[128 * 32];
  const int tid = threadIdx.x, lane = tid & 63, wave = tid >> 6;
  const int wr = wave >> 1, wc = wave & 1;
  const int l15 = lane & 15, g4 = lane >> 4;
  f32x4 acc[4][4] = {};
  for (int ks = 0; ks < 16; ++ks) {
    __syncthreads();
#pragma unroll
    for (int k = 0; k < 4; ++k) {
      int idx = k * 256 + tid;
      int row = idx >> 3, c4 = idx & 7;
      float4 v = *(const float4*)(X + (size_t)(Rbase + row) * 512 + ks * 32 + c4 * 4);
      f16x4 hv = { (f16)v.x, (f16)v.y, (f16)v.z, (f16)v.w };
      *(f16x4*)((char*)a_t + row * 80 + c4 * 8) = hv;
    }
#pragma unroll
    for (int i = 0; i < 2; ++i) {
      int o = i * 4096 + wave * 1024 + lane * 16;
      int r = o >> 6, cp = o & 63;
      gload16((const char*)WT + (size_t)(Cbase + r) * 1024 + ks * 64 + (cp ^ ((r & 3) << 4)),
              (char*)b_t + i * 4096 + wave * 1024);
    }
    __syncthreads();
    f16x8 af[4], bf[4];
#pragma unroll
    for (int mi = 0; mi < 4; ++mi) {
      int r = wr * 64 + mi * 16 + l15;
      af[mi] = *(const f16x8*)((const char*)a_t + r * 80 + g4 * 16);
    }
#pragma unroll
    for (int ni = 0; ni < 4; ++ni) {
      int r = wc * 64 + ni * 16 + l15;
      bf[ni] = *(const f16x8*)((const char*)b_t + r * 64 + ((g4 * 16) ^ ((r & 3) << 4)));
    }
#pragma unroll
    for (int mi = 0; mi < 4; ++mi)
#pragma unroll
      for (int ni = 0; ni < 4; ++ni)
        acc[mi][ni] = __builtin_amdgcn_mfma_f32_16x16x32_f16(af[mi], bf[ni], acc[mi][ni], 0, 0, 0);
  }
#pragma unroll
  for (int mi = 0; mi < 4; ++mi)
#pragma unroll
    for (int ni = 0; ni < 4; ++ni)
#pragma unroll
      for (int di = 0; di < 4; ++di) {
        int row = Rbase + wr * 64 + mi * 16 + g4 * 4 + di;
        int col = Cbase + wc * 64 + ni * 16 + l15;
        float v = acc[mi][ni][di];
        Out[(size_t)row * 256 + col] = (f16)(v > 0.f ? v : 0.f);
      }
}

// ---- flash attention, 32x32x16 f16 MFMA, swapped QK^T, BARRIER-FREE
// Operands loaded directly from global (L2) as per-lane 16B fragments.
// 256 blocks x 512 thr (8 waves = 4 qsub x 2 dvh); zero LDS, zero __syncthreads.
__global__ __launch_bounds__(512, 2) void attn_kernel(
    const float* __restrict__ X, const int* __restrict__ mask,
    const f16* __restrict__ Qh, const f16* __restrict__ Kh,
    const f16* __restrict__ VT, float* __restrict__ out) {
  // XCD-bijective swizzle: XCD (bid%8) serves logical blocks [x*32, x*32+31]
  // = exactly 2 batches -> 8 MB L2 working set per XCD instead of 64 MB.
  const int bid = blockIdx.x;
  const int lb = (bid & 7) * 32 + (bid >> 3);
  const int b = lb >> 4, qbase = (lb & 15) * 128;
  const int tid = threadIdx.x, lane = tid & 63, wave = tid >> 6;
  const int hi = lane >> 5, l31 = lane & 31;
  const int qsub = wave & 3, dvh = wave >> 2;

  // concat-copy: out[..., 512:1024] = inputs (fully coalesced)
#pragma unroll
  for (int k = 0; k < 32; ++k) {
    int f4 = k * 512 + tid;
    int row = f4 >> 7, c4 = f4 & 127;
    *(float4*)(out + (size_t)(b * LL + qbase + row) * DOUT + 512 + c4 * 4) =
        *(const float4*)(X + (size_t)(b * LL + qbase + row) * DIN + c4 * 4);
  }

  // hoist Q fragments: B-operand layout B[k=8*hi+i][col=q=lane&31]
  const int qr = qbase + qsub * 32 + l31;
  f16x8 Qf[16];
  {
    const f16x8* qrow = (const f16x8*)(Qh + (size_t)(b * LL + qr) * HH);
#pragma unroll
    for (int c = 0; c < 16; ++c) Qf[c] = qrow[2 * c + hi];
  }
  f32x16 acc[8] = {};
  float m_run = NEG_BIG, l_run = 0.f;
  const int* mrow = mask + b * LL;

  // per-lane fragment base pointers
  // K fragment row: m = mbase + l31, elems c*16 + hi*8 .. +8   (row = 256 f16)
  const f16* kb0 = Kh + (size_t)(b * LL + l31) * HH + hi * 8;
  // V fragment row: dv = dvh*256 + t*32 + l31, elems mbase + j*16 + hi*8 (row = 2048 f16)
  const f16* vb0 = VT + (size_t)(b * 512 + dvh * 256 + l31) * 2048 + hi * 8;

  for (int mt = 0; mt < 64; ++mt) {
    const int mbase = mt * 32;
    const f16* kb = kb0 + (size_t)mbase * HH;
    const f16* vb = vb0 + mbase;

    // ---- QK^T: S^T D[col=q=lane&31][row=m=(r&3)+8*(r>>2)+4*hi]; 2-chain ILP
    f32x16 s0 = {}, s1 = {};
#pragma unroll
    for (int c = 0; c < 8; ++c) {
      f16x8 kf0 = *(const f16x8*)(kb + (2 * c) * 16);
      f16x8 kf1 = *(const f16x8*)(kb + (2 * c + 1) * 16);
      s0 = __builtin_amdgcn_mfma_f32_32x32x16_f16(kf0, Qf[2 * c], s0, 0, 0, 0);
      s1 = __builtin_amdgcn_mfma_f32_32x32x16_f16(kf1, Qf[2 * c + 1], s1, 0, 0, 0);
    }
    f32x16 s;
#pragma unroll
    for (int r = 0; r < 16; ++r) s[r] = s0[r] + s1[r];

    // ---- softmax (reference semantics: select to -1e30)
    float tmax = NEG_BIG;
#pragma unroll
    for (int c2 = 0; c2 < 4; ++c2) {
      int4 mk = *(const int4*)(mrow + mbase + c2 * 8 + hi * 4);
      float x;
      x = s[4*c2+0] * SCALE; s[4*c2+0] = mk.x ? x : NEG_BIG;
      x = s[4*c2+1] * SCALE; s[4*c2+1] = mk.y ? x : NEG_BIG;
      x = s[4*c2+2] * SCALE; s[4*c2+2] = mk.z ? x : NEG_BIG;
      x = s[4*c2+3] * SCALE; s[4*c2+3] = mk.w ? x : NEG_BIG;
      tmax = fmaxf(tmax, fmaxf(fmaxf(s[4*c2+0], s[4*c2+1]), fmaxf(s[4*c2+2], s[4*c2+3])));
    }
    tmax = fmaxf(tmax, __shfl_xor(tmax, 32, 64));
    if (__any(tmax > m_run + 8.f)) {   // defer-max (T13, THR=8)
      float mnew = fmaxf(m_run, tmax);
      float alpha = __expf(m_run - mnew);
      m_run = mnew;
      l_run *= alpha;
#pragma unroll
      for (int r = 0; r < 16; ++r) {
        float ar = __shfl(alpha, (r & 3) + 8 * (r >> 2) + 4 * hi, 32);
#pragma unroll
        for (int t = 0; t < 8; ++t) acc[t][r] *= ar;
      }
    }
    float tsum = 0.f;
#pragma unroll
    for (int r = 0; r < 16; ++r) {
      float e = __expf(s[r] - m_run);
      s[r] = e;
      tsum += e;
    }
    tsum += __shfl_xor(tsum, 32, 64);
    l_run += tsum;

    // P relayout to A-operand: cvt_pkrtz pairs + permlane32_swap
    f16x8 pf[2];
#pragma unroll
    for (int j = 0; j < 2; ++j) {
      unsigned a0 = pk2(s[8*j+0], s[8*j+1]);
      unsigned a1 = pk2(s[8*j+2], s[8*j+3]);
      unsigned b0 = pk2(s[8*j+4], s[8*j+5]);
      unsigned b1 = pk2(s[8*j+6], s[8*j+7]);
      asm volatile("v_permlane32_swap_b32 %0, %1" : "+v"(a0), "+v"(b0));
      asm volatile("v_permlane32_swap_b32 %0, %1" : "+v"(a1), "+v"(b1));
      union { f16x8 v; unsigned u[4]; } un;
      un.u[0] = a0; un.u[1] = a1; un.u[2] = b0; un.u[3] = b1;
      pf[j] = un.v;
    }

    // ---- PV: acc[t] += P(32q x 16m) * V(16m x 32dv), V fragments from global
#pragma unroll
    for (int j = 0; j < 2; ++j)
#pragma unroll
      for (int t = 0; t < 8; ++t) {
        f16x8 vf = *(const f16x8*)(vb + (size_t)t * 32 * 2048 + j * 16);
        acc[t] = __builtin_amdgcn_mfma_f32_32x32x16_f16(pf[j], vf, acc[t], 0, 0, 0);
      }
  }

  // epilogue: divide by l (per-q via shfl), store context
  float linv = 1.f / l_run;
  float lr[16];
#pragma unroll
  for (int r = 0; r < 16; ++r) lr[r] = __shfl(linv, (r & 3) + 8 * (r >> 2) + 4 * hi, 32);
#pragma unroll
  for (int t = 0; t < 8; ++t) {
    int dv = dvh * 256 + t * 32 + l31;
#pragma unroll
    for (int r = 0; r < 16; ++r) {
      int q = qbase + qsub * 32 + (r & 3) + 8 * (r >> 2) + 4 * hi;
      out[(size_t)(b * LL + q) * DOUT + dv] = acc[t][r] * lr[r];
    }
  }
}

extern "C" void kernel_launch(void* const* d_in, const int* in_sizes, int n_in,
                              void* d_out, int out_size, void* d_ws, size_t ws_size,
                              hipStream_t stream) {
  const float* inputs = (const float*)d_in[0];
  const float* memory = (const float*)d_in[1];
  const int*   mmask  = (const int*)d_in[2];
  const float* W_in   = (const float*)d_in[3];
  const float* W_mem  = (const float*)d_in[4];
  float* out = (float*)d_out;

  char* ws = (char*)d_ws;
  f16* Qh  = (f16*)ws;                          // 16 MB
  f16* Kh  = (f16*)(ws + (16u << 20));          // 16 MB
  f16* VT  = (f16*)(ws + (32u << 20));          // 32 MB
  f16* WTi = (f16*)(ws + (64u << 20));          // 256 KB
  f16* WTm = (f16*)(ws + (64u << 20) + (1u << 18));

  wt_kernel<<<512, 256, 0, stream>>>(W_in, WTi);
  wt_kernel<<<512, 256, 0, stream>>>(W_mem, WTm);
  vt_kernel<<<dim3(64, 16, 16), 256, 0, stream>>>(memory, VT);
  proj_kernel<<<dim3(256, 2), 256, 0, stream>>>(inputs, WTi, Qh);
  proj_kernel<<<dim3(256, 2), 256, 0, stream>>>(memory, WTm, Kh);
  attn_kernel<<<256, 512, 0, stream>>>(inputs, mmask, Qh, Kh, VT, out);
}

// Round 6
// 341.118 us; speedup vs baseline: 1.8286x; 1.8286x over previous
//
#include <hip/hip_runtime.h>
#include <cstdint>
#include <cstddef>

typedef _Float16 f16;
typedef __attribute__((ext_vector_type(4)))  _Float16 f16x4;
typedef __attribute__((ext_vector_type(8)))  _Float16 f16x8;
typedef __attribute__((ext_vector_type(2)))  __fp16   fp16v2;
typedef __attribute__((ext_vector_type(4)))  float    f32x4;
typedef __attribute__((ext_vector_type(16))) float    f32x16;

static constexpr int BB = 16, LL = 2048, DIN = 512, HH = 256, DOUT = 1024;
static constexpr float SCALE = 0.0625f;   // 1/sqrt(256)
#define NEG_BIG (-1e30f)

__device__ __forceinline__ void gload16(const void* g, void* l) {
  __builtin_amdgcn_global_load_lds(
      (const __attribute__((address_space(1))) unsigned int*)g,
      (__attribute__((address_space(3))) unsigned int*)l, 16, 0, 0);
}

__device__ __forceinline__ unsigned pk2(float a, float b) {
  union { fp16v2 v; unsigned u; } c;
  c.v = __builtin_amdgcn_cvt_pkrtz(a, b);
  return c.u;
}

// exchange across the 32-lane halves via permlane32_swap (VALU, no LDS pipe)
__device__ __forceinline__ float xchg32(float x, int hi) {
  union { float f; unsigned u; } a, b;
  a.f = x; b.f = x;
  asm volatile("v_permlane32_swap_b32 %0, %1" : "+v"(a.u), "+v"(b.u));
  // lanes <32: partner value in b; lanes >=32: in a
  return hi ? a.f : b.f;
}

// ---- W transpose+cast: W[512][256] f32 -> WT[256][512] f16
__global__ void wt_kernel(const float* __restrict__ W, f16* __restrict__ WT) {
  int g = blockIdx.x * 256 + threadIdx.x;     // 131072 total
  int d = g >> 8, h = g & 255;
  WT[h * 512 + d] = (f16)W[g];
}

// ---- V transpose+cast: mem[b][m][512] f32 -> VT[b][512][2048] f16
__global__ void vt_kernel(const float* __restrict__ mem, f16* __restrict__ VT) {
  int m0 = blockIdx.x * 32, d0 = blockIdx.y * 32, b = blockIdx.z;
  __shared__ f16 t[32][36];
  int tid = threadIdx.x;
  {
    int r = tid >> 3, c4 = (tid & 7) * 4;
    float4 v = *(const float4*)(mem + (size_t)(b * LL + m0 + r) * DIN + d0 + c4);
    t[c4 + 0][r] = (f16)v.x; t[c4 + 1][r] = (f16)v.y;
    t[c4 + 2][r] = (f16)v.z; t[c4 + 3][r] = (f16)v.w;
  }
  __syncthreads();
  {
    int d = tid >> 3, seg = tid & 7;
    f16x4 hv = *(const f16x4*)&t[d][seg * 4];
    *(f16x4*)(VT + (size_t)(b * 512 + d0 + d) * 2048 + m0 + seg * 4) = hv;
  }
}

// ---- projection: Out[M][256] = f16(relu(X[M][512] * W)), W given as WT[256][512] f16
__global__ __launch_bounds__(256, 2) void proj_kernel(const float* __restrict__ X,
                                                      const f16* __restrict__ WT,
                                                      f16* __restrict__ Out) {
  const int Rbase = blockIdx.x * 128, Cbase = blockIdx.y * 128;
  __shared__ f16 a_t[128 * 40];
  __shared__ f16 b_t[128 * 32];
  const int tid = threadIdx.x, lane = tid & 63, wave = tid >> 6;
  const int wr = wave >> 1, wc = wave & 1;
  const int l15 = lane & 15, g4 = lane >> 4;
  f32x4 acc[4][4] = {};
  for (int ks = 0; ks < 16; ++ks) {
    __syncthreads();
#pragma unroll
    for (int k = 0; k < 4; ++k) {
      int idx = k * 256 + tid;
      int row = idx >> 3, c4 = idx & 7;
      float4 v = *(const float4*)(X + (size_t)(Rbase + row) * 512 + ks * 32 + c4 * 4);
      f16x4 hv = { (f16)v.x, (f16)v.y, (f16)v.z, (f16)v.w };
      *(f16x4*)((char*)a_t + row * 80 + c4 * 8) = hv;
    }
#pragma unroll
    for (int i = 0; i < 2; ++i) {
      int o = i * 4096 + wave * 1024 + lane * 16;
      int r = o >> 6, cp = o & 63;
      gload16((const char*)WT + (size_t)(Cbase + r) * 1024 + ks * 64 + (cp ^ ((r & 3) << 4)),
              (char*)b_t + i * 4096 + wave * 1024);
    }
    __syncthreads();
    f16x8 af[4], bf[4];
#pragma unroll
    for (int mi = 0; mi < 4; ++mi) {
      int r = wr * 64 + mi * 16 + l15;
      af[mi] = *(const f16x8*)((const char*)a_t + r * 80 + g4 * 16);
    }
#pragma unroll
    for (int ni = 0; ni < 4; ++ni) {
      int r = wc * 64 + ni * 16 + l15;
      bf[ni] = *(const f16x8*)((const char*)b_t + r * 64 + ((g4 * 16) ^ ((r & 3) << 4)));
    }
#pragma unroll
    for (int mi = 0; mi < 4; ++mi)
#pragma unroll
      for (int ni = 0; ni < 4; ++ni)
        acc[mi][ni] = __builtin_amdgcn_mfma_f32_16x16x32_f16(af[mi], bf[ni], acc[mi][ni], 0, 0, 0);
  }
#pragma unroll
  for (int mi = 0; mi < 4; ++mi)
#pragma unroll
    for (int ni = 0; ni < 4; ++ni)
#pragma unroll
      for (int di = 0; di < 4; ++di) {
        int row = Rbase + wr * 64 + mi * 16 + g4 * 4 + di;
        int col = Cbase + wc * 64 + ni * 16 + l15;
        float v = acc[mi][ni][di];
        Out[(size_t)row * 256 + col] = (f16)(v > 0.f ? v : 0.f);
      }
}

// ---- flash attention, 32x32x16 f16 MFMA, swapped QK^T, double-buffered staging
// block: 512 thr = 8 waves = 4 q-subs (32 q each) x 2 dv-halves (256 dv each)
// grid: 16 batches x 16 q-tiles(128) = 256 blocks, 1 block/CU
__global__ __launch_bounds__(512, 2) void attn_kernel(
    const float* __restrict__ X, const int* __restrict__ mask,
    const f16* __restrict__ Qh, const f16* __restrict__ Kh,
    const f16* __restrict__ VT, float* __restrict__ out) {
  const int blk = blockIdx.x, b = blk >> 4, qbase = (blk & 15) * 128;
  const int tid = threadIdx.x, lane = tid & 63, wave = tid >> 6;
  const int hi = lane >> 5, l31 = lane & 31;
  const int qsub = wave & 3, dvh = wave >> 2;
  __shared__ f16 KtBuf[2][32 * 256];   // 2 x 16 KB, rows 512 B, XOR((m&31)<<4)
  __shared__ f16 VtBuf[2][512 * 32];   // 2 x 32 KB, rows 64 B,  XOR(((dv>>1)&3)<<4)
  __shared__ float Bias[2048];         // 8 KB: mask ? 0 : -1e30 (f32), per batch

  // concat-copy: out[..., 512:1024] = inputs (fully coalesced)
#pragma unroll
  for (int k = 0; k < 32; ++k) {
    int f4 = k * 512 + tid;
    int row = f4 >> 7, c4 = f4 & 127;
    *(float4*)(out + (size_t)(b * LL + qbase + row) * DOUT + 512 + c4 * 4) =
        *(const float4*)(X + (size_t)(b * LL + qbase + row) * DIN + c4 * 4);
  }
  // mask row -> f32 bias in LDS (once)
  {
    int4 mv = *(const int4*)(mask + b * LL + tid * 4);
    float4 bv = { mv.x ? 0.f : NEG_BIG, mv.y ? 0.f : NEG_BIG,
                  mv.z ? 0.f : NEG_BIG, mv.w ? 0.f : NEG_BIG };
    *(float4*)&Bias[tid * 4] = bv;
  }

  // hoist Q fragments: B-operand layout B[k=8*hi+i][col=q=lane&31]
  const int qr = qbase + qsub * 32 + l31;
  f16x8 Qf[16];
  {
    const f16x8* qrow = (const f16x8*)(Qh + (size_t)(b * LL + qr) * HH);
#pragma unroll
    for (int c = 0; c < 16; ++c) Qf[c] = qrow[2 * c + hi];
  }
  f32x16 acc[8] = {};
  float m_run = NEG_BIG, l_run = 0.f;

  // stage tile -> buffer bufi (6 gload_lds per thread: 2 K + 4 V)
  auto stage = [&](int bufi, int mbase) {
#pragma unroll
    for (int i = 0; i < 2; ++i) {           // K tile [32][256]
      int o = i * 8192 + wave * 1024 + lane * 16;
      int r = o >> 9, cp = o & 511;
      gload16((const char*)Kh + (size_t)(b * LL + mbase + r) * 512 + (cp ^ ((r & 31) << 4)),
              (char*)KtBuf[bufi] + i * 8192 + wave * 1024);
    }
#pragma unroll
    for (int i = 0; i < 4; ++i) {           // V^T tile [512][32]
      int o = i * 8192 + wave * 1024 + lane * 16;
      int dv = o >> 6, cp = o & 63;
      gload16((const char*)VT + (size_t)(b * 512 + dv) * 4096 + mbase * 2 + (cp ^ (((dv >> 1) & 3) << 4)),
              (char*)VtBuf[bufi] + i * 8192 + wave * 1024);
    }
  };

  stage(0, 0);
  __syncthreads();   // Bias + first tile visible (single full drain)

  for (int mt = 0; mt < 64; ++mt) {
    const int cur = mt & 1;
    const int mbase = mt * 32;
    // prefetch next tile (wraps at the end: harmless redundant reload of tile 0)
    stage(cur ^ 1, ((mt + 1) & 63) * 32);
    // wait only for THIS tile's 6 loads (issued one iteration ago); 6 newest stay in flight
    asm volatile("s_waitcnt vmcnt(6)" ::: "memory");
    __builtin_amdgcn_sched_barrier(0);
    __builtin_amdgcn_s_barrier();

    const char* kb = (const char*)KtBuf[cur];
    const char* vb = (const char*)VtBuf[cur];

    // S^T tile: D[col=q=lane&31][row=m=(r&3)+8*(r>>2)+4*hi]; 2-chain ILP split
    f32x16 s0 = {}, s1 = {};
    __builtin_amdgcn_s_setprio(1);
#pragma unroll
    for (int c = 0; c < 8; ++c) {
      f16x8 kf0 = *(const f16x8*)(kb + l31 * 512 + (((2 * c) * 32 + hi * 16) ^ (l31 << 4)));
      f16x8 kf1 = *(const f16x8*)(kb + l31 * 512 + (((2 * c + 1) * 32 + hi * 16) ^ (l31 << 4)));
      s0 = __builtin_amdgcn_mfma_f32_32x32x16_f16(kf0, Qf[2 * c], s0, 0, 0, 0);
      s1 = __builtin_amdgcn_mfma_f32_32x32x16_f16(kf1, Qf[2 * c + 1], s1, 0, 0, 0);
    }
    __builtin_amdgcn_s_setprio(0);
    f32x16 s;
#pragma unroll
    for (int r = 0; r < 16; ++r) s[r] = s0[r] + s1[r];

    // scale + mask-bias (s*SCALE + bias; bias = 0 or -1e30, bit-identical to reference)
    float tmax = NEG_BIG;
#pragma unroll
    for (int c2 = 0; c2 < 4; ++c2) {
      f32x4 bv = *(const f32x4*)&Bias[mbase + c2 * 8 + hi * 4];
#pragma unroll
      for (int i = 0; i < 4; ++i) {
        s[4 * c2 + i] = s[4 * c2 + i] * SCALE + bv[i];
      }
      tmax = fmaxf(tmax, fmaxf(fmaxf(s[4*c2+0], s[4*c2+1]), fmaxf(s[4*c2+2], s[4*c2+3])));
    }
    tmax = fmaxf(tmax, xchg32(tmax, hi));
    if (__any(tmax > m_run + 8.f)) {   // defer-max (T13, THR=8)
      float mnew = fmaxf(m_run, tmax);
      float alpha = __expf(m_run - mnew);
      m_run = mnew;
      l_run *= alpha;
#pragma unroll
      for (int r = 0; r < 16; ++r) {
        float ar = __shfl(alpha, (r & 3) + 8 * (r >> 2) + 4 * hi, 32);
#pragma unroll
        for (int t = 0; t < 8; ++t) acc[t][r] *= ar;
      }
    }
    float tsum = 0.f;
#pragma unroll
    for (int r = 0; r < 16; ++r) {
      float e = __expf(s[r] - m_run);
      s[r] = e;
      tsum += e;
    }
    tsum += xchg32(tsum, hi);
    l_run += tsum;

    // P relayout to A-operand: cvt_pkrtz pairs + permlane32_swap
    f16x8 pf[2];
#pragma unroll
    for (int j = 0; j < 2; ++j) {
      unsigned a0 = pk2(s[8*j+0], s[8*j+1]);
      unsigned a1 = pk2(s[8*j+2], s[8*j+3]);
      unsigned b0 = pk2(s[8*j+4], s[8*j+5]);
      unsigned b1 = pk2(s[8*j+6], s[8*j+7]);
      asm volatile("v_permlane32_swap_b32 %0, %1" : "+v"(a0), "+v"(b0));
      asm volatile("v_permlane32_swap_b32 %0, %1" : "+v"(a1), "+v"(b1));
      union { f16x8 v; unsigned u[4]; } un;
      un.u[0] = a0; un.u[1] = a1; un.u[2] = b0; un.u[3] = b1;
      pf[j] = un.v;
    }
    // PV: acc[t] += P(32q x 16m) * V(16m x 32dv)
    __builtin_amdgcn_s_setprio(1);
#pragma unroll
    for (int j = 0; j < 2; ++j)
#pragma unroll
      for (int t = 0; t < 8; ++t) {
        int dvl = dvh * 256 + t * 32 + l31;
        f16x8 vf = *(const f16x8*)(vb + dvl * 64 + ((j * 32 + hi * 16) ^ (((dvl >> 1) & 3) << 4)));
        acc[t] = __builtin_amdgcn_mfma_f32_32x32x16_f16(pf[j], vf, acc[t], 0, 0, 0);
      }
    __builtin_amdgcn_s_setprio(0);
    // WAR guard: next iter's stage overwrites buf[cur] — all reads above are done
    __builtin_amdgcn_s_barrier();
  }

  // epilogue: divide by l (per-q via shfl), store context
  float linv = 1.f / l_run;
  float lr[16];
#pragma unroll
  for (int r = 0; r < 16; ++r) lr[r] = __shfl(linv, (r & 3) + 8 * (r >> 2) + 4 * hi, 32);
#pragma unroll
  for (int t = 0; t < 8; ++t) {
    int dv = dvh * 256 + t * 32 + l31;
#pragma unroll
    for (int r = 0; r < 16; ++r) {
      int q = qbase + qsub * 32 + (r & 3) + 8 * (r >> 2) + 4 * hi;
      out[(size_t)(b * LL + q) * DOUT + dv] = acc[t][r] * lr[r];
    }
  }
}

extern "C" void kernel_launch(void* const* d_in, const int* in_sizes, int n_in,
                              void* d_out, int out_size, void* d_ws, size_t ws_size,
                              hipStream_t stream) {
  const float* inputs = (const float*)d_in[0];
  const float* memory = (const float*)d_in[1];
  const int*   mmask  = (const int*)d_in[2];
  const float* W_in   = (const float*)d_in[3];
  const float* W_mem  = (const float*)d_in[4];
  float* out = (float*)d_out;

  char* ws = (char*)d_ws;
  f16* Qh  = (f16*)ws;                          // 16 MB
  f16* Kh  = (f16*)(ws + (16u << 20));          // 16 MB
  f16* VT  = (f16*)(ws + (32u << 20));          // 32 MB
  f16* WTi = (f16*)(ws + (64u << 20));          // 256 KB
  f16* WTm = (f16*)(ws + (64u << 20) + (1u << 18));

  wt_kernel<<<512, 256, 0, stream>>>(W_in, WTi);
  wt_kernel<<<512, 256, 0, stream>>>(W_mem, WTm);
  vt_kernel<<<dim3(64, 16, 16), 256, 0, stream>>>(memory, VT);
  proj_kernel<<<dim3(256, 2), 256, 0, stream>>>(inputs, WTi, Qh);
  proj_kernel<<<dim3(256, 2), 256, 0, stream>>>(memory, WTm, Kh);
  attn_kernel<<<256, 512, 0, stream>>>(inputs, mmask, Qh, Kh, VT, out);
}